// Round 3
// baseline (270.170 us; speedup 1.0000x reference)
//
#include <hip/hip_runtime.h>

#define N_NODES 2048
#define N_EDGES 65536
#define NV 6
#define C 32

typedef float f2 __attribute__((ext_vector_type(2)));

// ---------------------------------------------------------------------------
// ws layout (ints, then floats), all offsets 16B-aligned:
//   cnt_i  [2048]  (zeroed)   degree histogram
//   cursor [2048]  (zeroed)   scatter cursors
//   rowptr [2049]             CSR row pointers
//   eid    [65536]            CSR edge ids (sorted by dst)
//   msg    [65536*32] f32     per-edge messages (rewritten each layer)
//   h1,h2,h3 [2048*32] f32    node features
// ---------------------------------------------------------------------------

// ---- CSR build (dst is identical for all 3 layers: build once) ----
__global__ void hist_kernel(const int* __restrict__ dst, int* __restrict__ cnt) {
    int e = blockIdx.x * blockDim.x + threadIdx.x;
    if (e < N_EDGES) atomicAdd(&cnt[dst[e]], 1);
}

__global__ __launch_bounds__(256) void scan_kernel(const int* __restrict__ cnt,
                                                   int* __restrict__ rowptr) {
    __shared__ int part[256];
    const int tid = threadIdx.x;
    int local[8];
    int s = 0;
#pragma unroll
    for (int k = 0; k < 8; k++) { local[k] = cnt[tid * 8 + k]; s += local[k]; }
    part[tid] = s;
    __syncthreads();
    for (int off = 1; off < 256; off <<= 1) {
        int v = (tid >= off) ? part[tid - off] : 0;
        __syncthreads();
        part[tid] += v;
        __syncthreads();
    }
    int run = part[tid] - s;  // exclusive prefix
#pragma unroll
    for (int k = 0; k < 8; k++) { rowptr[tid * 8 + k] = run; run += local[k]; }
    if (tid == 255) rowptr[2048] = run;  // == N_EDGES
}

__global__ void scatter_kernel(const int* __restrict__ dst, const int* __restrict__ rowptr,
                               int* __restrict__ cursor, int* __restrict__ eid) {
    int e = blockIdx.x * blockDim.x + threadIdx.x;
    if (e < N_EDGES) {
        int d = dst[e];
        int pos = atomicAdd(&cursor[d], 1);
        eid[rowptr[d] + pos] = e;
    }
}

// ---- Layer 1 edge messages (in_c = 1): msg[e*32+o] = x[src]*relu(ea@W1+b1)[o]
// thread id t == e*32+o, so the msg store is perfectly coalesced. No atomics.
__global__ void edge1_kernel(const float* __restrict__ x,
                             const float* __restrict__ ea,
                             const int* __restrict__ src,
                             const float* __restrict__ W1,
                             const float* __restrict__ b1,
                             float* __restrict__ msg) {
    int t = blockIdx.x * blockDim.x + threadIdx.x;
    int e = t >> 5, o = t & 31;
    if (e >= N_EDGES) return;
    const float* eap = ea + e * NV;
    float w = b1[o];
#pragma unroll
    for (int v = 0; v < NV; v++) w = fmaf(eap[v], W1[v * C + o], w);
    msg[t] = x[src[e]] * fmaxf(w, 0.0f);
}

// ---- Layers 2/3 edge messages: one wave per 8 edges (W LDS reads amortized 8x).
// lane l: o = l&31, i-range [ (l>>5)*16, +16 ). W+b in LDS stride-32 (0 conflicts,
// verified R1/R2). h[src] staged per-wave as hb[i][k], read as broadcast b128.
// float2 math so the 6-FMA MLP can map to v_pk_fma_f32. Plain msg stores.
__global__ __launch_bounds__(256) void edge23_kernel(
    const float* __restrict__ hprev,   // [N, 32]
    const float* __restrict__ ea,      // [E, 6]
    const int* __restrict__ src,
    const float* __restrict__ W,       // [NV, 1024]
    const float* __restrict__ b,       // [1024]
    float* __restrict__ msg)           // [E, 32]
{
    __shared__ float Wall[7 * 1024];   // planes 0..5 = W, plane 6 = b (28 KB)
    __shared__ float hb[4][32 * 8];    // per-wave staging [i][k] (4 KB)
    for (int i = threadIdx.x; i < 6 * 1024; i += 256) Wall[i] = W[i];
    for (int i = threadIdx.x; i < 1024; i += 256) Wall[6 * 1024 + i] = b[i];
    __syncthreads();

    const int lane = threadIdx.x & 63;
    const int o = lane & 31;
    const int i0 = (lane >> 5) * 16;
    const int w = threadIdx.x >> 6;
    const int wid = (blockIdx.x * 256 + threadIdx.x) >> 6;
    const int nwaves = (gridDim.x * 256) >> 6;
    const int kq = (lane >> 5) << 2;   // half-wave 0 stages edges 0..3, half 1: 4..7
    float* hbw = &hb[w][0];

    for (int g = wid; g < N_EDGES / 8; g += nwaves) {
        const int e0 = g * 8;
        const int4 sq = *(const int4*)&src[e0 + kq];
        // all 48 ea floats for the 8 edges (contiguous, 16B-aligned since e0%8==0)
        union { float4 q[12]; float f[48]; } eau;
        const float4* eap4 = (const float4*)(ea + (size_t)e0 * NV);
#pragma unroll
        for (int t = 0; t < 12; t++) eau.q[t] = eap4[t];
        // stage h[src_k][o] -> hb[o][k]  (per-wave private; DS ops are in-order)
        float4 hq;
        hq.x = hprev[sq.x * C + o];
        hq.y = hprev[sq.y * C + o];
        hq.z = hprev[sq.z * C + o];
        hq.w = hprev[sq.w * C + o];
        *(float4*)&hbw[o * 8 + kq] = hq;
        // pack ea into edge-pair float2s: p[a][v] = {ea[2a][v], ea[2a+1][v]}
        f2 p[4][6];
#pragma unroll
        for (int a = 0; a < 4; a++)
#pragma unroll
            for (int v = 0; v < 6; v++)
                p[a][v] = (f2){eau.f[a * 12 + v], eau.f[a * 12 + 6 + v]};

        f2 acc[4] = {(f2)(0.0f), (f2)(0.0f), (f2)(0.0f), (f2)(0.0f)};
        const f2 zero2 = (f2)(0.0f);
#pragma unroll
        for (int j = 0; j < 16; j++) {
            const int idx = (i0 + j) * C + o;
            const float w0 = Wall[idx];
            const float w1 = Wall[1024 + idx];
            const float w2 = Wall[2048 + idx];
            const float w3 = Wall[3072 + idx];
            const float w4 = Wall[4096 + idx];
            const float w5 = Wall[5120 + idx];
            const float bb = Wall[6144 + idx];
            const float4 h03 = *(const float4*)&hbw[(i0 + j) * 8];
            const float4 h47 = *(const float4*)&hbw[(i0 + j) * 8 + 4];
            const f2 hp[4] = {(f2){h03.x, h03.y}, (f2){h03.z, h03.w},
                              (f2){h47.x, h47.y}, (f2){h47.z, h47.w}};
            const f2 W0 = (f2)(w0), W1v = (f2)(w1), W2v = (f2)(w2);
            const f2 W3v = (f2)(w3), W4v = (f2)(w4), W5v = (f2)(w5);
            const f2 BB = (f2)(bb);
#pragma unroll
            for (int a = 0; a < 4; a++) {
                f2 t = BB;
                t += p[a][0] * W0;
                t += p[a][1] * W1v;
                t += p[a][2] * W2v;
                t += p[a][3] * W3v;
                t += p[a][4] * W4v;
                t += p[a][5] * W5v;
                t = __builtin_elementwise_max(t, zero2);
                acc[a] += hp[a] * t;
            }
        }
        float accs[8];
#pragma unroll
        for (int a = 0; a < 4; a++) { accs[2 * a] = acc[a].x; accs[2 * a + 1] = acc[a].y; }
#pragma unroll
        for (int k = 0; k < 8; k++) accs[k] += __shfl_down(accs[k], 32);
        if (lane < 32) {
            float* mp = msg + (size_t)e0 * C + o;
#pragma unroll
            for (int k = 0; k < 8; k++) mp[k * C] = accs[k];
        }
    }
}

// ---- Aggregation + node update fused: hout = relu(mean(msg over in-edges)
//      + hprev@root + bias). Half-wave per node, no atomics, degree from CSR.
template <int IN_C>
__global__ __launch_bounds__(256) void gather_kernel(
    const float* __restrict__ msg, const int* __restrict__ rowptr,
    const int* __restrict__ eid, const float* __restrict__ hprev,
    const float* __restrict__ root,   // [IN_C, 32]
    const float* __restrict__ bias,   // [32]
    float* __restrict__ hout) {       // [N, 32]
    const int o = threadIdx.x & 31;
    const int n = blockIdx.x * 8 + (threadIdx.x >> 5);
    const int beg = rowptr[n], end = rowptr[n + 1];
    float acc = 0.0f;
    int k = beg;
    for (; k + 4 <= end; k += 4) {  // 4 loads in flight per iter
        int ka = eid[k], kb = eid[k + 1], kc = eid[k + 2], kd = eid[k + 3];
        float m0 = msg[ka * C + o];
        float m1 = msg[kb * C + o];
        float m2 = msg[kc * C + o];
        float m3 = msg[kd * C + o];
        acc += (m0 + m1) + (m2 + m3);
    }
    for (; k < end; k++) acc += msg[eid[k] * C + o];
    const float inv = 1.0f / fmaxf((float)(end - beg), 1.0f);
    float r = fmaf(acc, inv, bias[o]);
#pragma unroll
    for (int i = 0; i < IN_C; i++) r = fmaf(hprev[n * IN_C + i], root[i * C + o], r);
    hout[n * C + o] = fmaxf(r, 0.0f);
}

// ---- CBT: out[i,j] = sum_k |h[i,k]-h[j,k]| (unchanged from R2)
__global__ __launch_bounds__(256) void cbt_kernel(const float* __restrict__ h,
                                                  float* __restrict__ out) {
    __shared__ float hj_s[64][33];
    __shared__ float hi_s[64 * 32];
    const int lane = threadIdx.x & 63;
    const int w = threadIdx.x >> 6;
    const int j0 = blockIdx.x * 64;
    const int i0 = blockIdx.y * 64;
    for (int t = threadIdx.x; t < 64 * 32; t += 256) {
        hj_s[t >> 5][t & 31] = h[j0 * 32 + t];
        hi_s[t] = h[i0 * 32 + t];
    }
    __syncthreads();
    float hj[32];
#pragma unroll
    for (int k = 0; k < 32; k++) hj[k] = hj_s[lane][k];
    const int j = j0 + lane;
#pragma unroll 4
    for (int ii = w * 16; ii < w * 16 + 16; ii++) {
        float acc = 0.0f;
#pragma unroll
        for (int k = 0; k < 32; k++) {
            acc += fabsf(hi_s[ii * 32 + k] - hj[k]);
        }
        out[(size_t)(i0 + ii) * N_NODES + j] = acc;
    }
}

extern "C" void kernel_launch(void* const* d_in, const int* in_sizes, int n_in,
                              void* d_out, int out_size, void* d_ws, size_t ws_size,
                              hipStream_t stream) {
    const float* x         = (const float*)d_in[0];
    const float* edge_attr = (const float*)d_in[1];
    const int*   edge_idx  = (const int*)d_in[2];
    const float* W1 = (const float*)d_in[3];
    const float* b1 = (const float*)d_in[4];
    const float* root1 = (const float*)d_in[5];
    const float* bias1 = (const float*)d_in[6];
    const float* W2 = (const float*)d_in[7];
    const float* b2 = (const float*)d_in[8];
    const float* root2 = (const float*)d_in[9];
    const float* bias2 = (const float*)d_in[10];
    const float* W3 = (const float*)d_in[11];
    const float* b3 = (const float*)d_in[12];
    const float* root3 = (const float*)d_in[13];
    const float* bias3 = (const float*)d_in[14];

    const int* src = edge_idx;            // row 0
    const int* dst = edge_idx + N_EDGES;  // row 1

    int* wsi    = (int*)d_ws;
    int* cnt_i  = wsi;              // 2048
    int* cursor = wsi + 2048;       // 2048
    int* rowptr = wsi + 4096;       // 2049
    int* eid    = wsi + 6160;       // 65536 (6160 keeps 16B alignment)
    float* msg  = (float*)(wsi + 6160 + 65536);  // E*32
    float* h1   = msg + (size_t)N_EDGES * C;
    float* h2   = h1 + N_NODES * C;
    float* h3   = h2 + N_NODES * C;

    // zero cnt_i + cursor (16 KB)
    hipMemsetAsync(d_ws, 0, 4096 * sizeof(int), stream);

    // CSR build (dst shared by all layers)
    hist_kernel<<<N_EDGES / 256, 256, 0, stream>>>(dst, cnt_i);
    scan_kernel<<<1, 256, 0, stream>>>(cnt_i, rowptr);
    scatter_kernel<<<N_EDGES / 256, 256, 0, stream>>>(dst, rowptr, cursor, eid);

    // Layer 1
    edge1_kernel<<<(N_EDGES * C) / 256, 256, 0, stream>>>(x, edge_attr, src, W1, b1, msg);
    gather_kernel<1><<<N_NODES / 8, 256, 0, stream>>>(msg, rowptr, eid, x, root1, bias1, h1);

    // Layer 2
    edge23_kernel<<<2048, 256, 0, stream>>>(h1, edge_attr, src, W2, b2, msg);
    gather_kernel<C><<<N_NODES / 8, 256, 0, stream>>>(msg, rowptr, eid, h1, root2, bias2, h2);

    // Layer 3
    edge23_kernel<<<2048, 256, 0, stream>>>(h2, edge_attr, src, W3, b3, msg);
    gather_kernel<C><<<N_NODES / 8, 256, 0, stream>>>(msg, rowptr, eid, h2, root3, bias3, h3);

    // CBT
    cbt_kernel<<<dim3(N_NODES / 64, N_NODES / 64), 256, 0, stream>>>(h3, (float*)d_out);
}

// Round 4
// 169.384 us; speedup vs baseline: 1.5950x; 1.5950x over previous
//
#include <hip/hip_runtime.h>

#define N_NODES 2048
#define N_EDGES 65536
#define NV 6
#define C 32

// ---------------------------------------------------------------------------
// ws layout (floats):
//   [0, N)            : cnt   (in-degree per node, fp32)   -- zeroed
//   [N, N+3*N*C)      : sum1, sum2, sum3 (scatter-add)     -- zeroed
//   [N+3NC, N+6NC)    : h1, h2, h3 (node features)         -- fully overwritten
// ---------------------------------------------------------------------------

// Layer 1 (in_c = 1), degree count fused (o==0 lane).
__global__ void edge1_kernel(const float* __restrict__ x,
                             const float* __restrict__ ea,
                             const int* __restrict__ src,
                             const int* __restrict__ dst,
                             const float* __restrict__ W1,
                             const float* __restrict__ b1,
                             float* __restrict__ sum1,
                             float* __restrict__ cnt) {
    int t = blockIdx.x * blockDim.x + threadIdx.x;
    int e = t >> 5, o = t & 31;
    if (e >= N_EDGES) return;
    const float* eap = ea + e * NV;
    float w = b1[o];
#pragma unroll
    for (int v = 0; v < NV; v++) w = fmaf(eap[v], W1[v * C + o], w);
    w = fmaxf(w, 0.0f);
    int d = dst[e];
    atomicAdd(&sum1[d * C + o], x[src[e]] * w);
    if (o == 0) atomicAdd(&cnt[d], 1.0f);
}

// Finalize a layer: h_out = relu(sum/max(cnt,1) + h_prev @ root + bias)
template <int IN_C>
__global__ void node_kernel(const float* __restrict__ sum,
                            const float* __restrict__ cnt,
                            const float* __restrict__ hprev,
                            const float* __restrict__ root,  // [IN_C, C]
                            const float* __restrict__ bias,  // [C]
                            float* __restrict__ hout) {
    int t = blockIdx.x * blockDim.x + threadIdx.x;  // N*C threads
    int n = t >> 5, o = t & 31;
    float inv = 1.0f / fmaxf(cnt[n], 1.0f);
    float acc = sum[t] * inv + bias[o];
#pragma unroll
    for (int i = 0; i < IN_C; i++) acc = fmaf(hprev[n * IN_C + i], root[i * C + o], acc);
    hout[t] = fmaxf(acc, 0.0f);
}

// Layers 2/3: one wave per 8-edge group, exactly one group per wave.
// lane l: o = l&31, half = l>>5, i-range [half*16, +16).
// W (6 planes) in LDS stride-32 reads: lane o -> bank o, 2-way half-wave
// alias = free (0 conflicts verified R1/R2). Bias held in 16 regs/lane.
// h staging: half 0 writes edges A(0..3) into hb[0..127], half 1 writes
// edges B(4..7) into hb[128..255] -- one fully contiguous 1KB
// ds_write_b128 per wave, conflict-free (R2's proven pattern).
__global__ __launch_bounds__(256, 4) void edge23_kernel(
    const float* __restrict__ hprev,   // [N, 32]
    const float* __restrict__ ea,      // [E, 6]
    const int* __restrict__ src,
    const int* __restrict__ dst,
    const float* __restrict__ W,       // [NV, 1024]
    const float* __restrict__ b,       // [1024]
    float* __restrict__ sumout)        // [N, 32]
{
    __shared__ float Wall[6 * 1024];   // 24 KB
    __shared__ float hb[4][256];       // per-wave staging: [i*4+k] (A), 128+[i*4+k] (B)
    for (int i = threadIdx.x; i < 6 * 1024; i += 256) Wall[i] = W[i];
    __syncthreads();

    const int lane = threadIdx.x & 63;
    const int o = lane & 31;
    const int half = lane >> 5;
    const int i0 = half * 16;
    const int w = threadIdx.x >> 6;
    const int g = (blockIdx.x * 256 + threadIdx.x) >> 6;  // 8192 waves == 8192 groups
    const int e0 = g * 8;
    float* hbw = &hb[w][0];

    // bias rows for this lane's i-range, once per wave (L1/L2-resident)
    float breg[16];
#pragma unroll
    for (int j = 0; j < 16; j++) breg[j] = b[(i0 + j) * C + o];

    // 8 edges' attrs: 48 contiguous floats (16B-aligned, e0 % 8 == 0)
    float eaf[48];
    const float4* eap4 = (const float4*)(ea + (size_t)e0 * NV);
#pragma unroll
    for (int t = 0; t < 12; t++) *(float4*)&eaf[t * 4] = eap4[t];

    // stage h[src]: half 0 loads edges 0..3, half 1 loads edges 4..7
    const int4 sq = *(const int4*)&src[e0 + half * 4];
    float4 hq;
    hq.x = hprev[sq.x * C + o];
    hq.y = hprev[sq.y * C + o];
    hq.z = hprev[sq.z * C + o];
    hq.w = hprev[sq.w * C + o];
    *(float4*)&hbw[half * 128 + o * 4] = hq;  // contiguous 1KB wave write

    float acc[8] = {0, 0, 0, 0, 0, 0, 0, 0};
#pragma unroll
    for (int j = 0; j < 16; j++) {
        const int idx = (i0 + j) * C + o;
        const float w0 = Wall[idx];
        const float w1 = Wall[1024 + idx];
        const float w2 = Wall[2048 + idx];
        const float w3 = Wall[3072 + idx];
        const float w4 = Wall[4096 + idx];
        const float w5 = Wall[5120 + idx];
        const float bb = breg[j];
        const float4 hA = *(const float4*)&hbw[(i0 + j) * 4];        // broadcast
        const float4 hB = *(const float4*)&hbw[128 + (i0 + j) * 4];  // broadcast
        const float hv[8] = {hA.x, hA.y, hA.z, hA.w, hB.x, hB.y, hB.z, hB.w};
#pragma unroll
        for (int k = 0; k < 8; k++) {
            const float* eap = &eaf[k * 6];
            float t = bb;
            t = fmaf(eap[0], w0, t);
            t = fmaf(eap[1], w1, t);
            t = fmaf(eap[2], w2, t);
            t = fmaf(eap[3], w3, t);
            t = fmaf(eap[4], w4, t);
            t = fmaf(eap[5], w5, t);
            acc[k] = fmaf(hv[k], fmaxf(t, 0.0f), acc[k]);
        }
    }
#pragma unroll
    for (int k = 0; k < 8; k++) acc[k] += __shfl_down(acc[k], 32);

    const int4 dA = *(const int4*)&dst[e0];
    const int4 dB = *(const int4*)&dst[e0 + 4];
    if (lane < 32) {
        atomicAdd(&sumout[dA.x * C + o], acc[0]);
        atomicAdd(&sumout[dA.y * C + o], acc[1]);
        atomicAdd(&sumout[dA.z * C + o], acc[2]);
        atomicAdd(&sumout[dA.w * C + o], acc[3]);
        atomicAdd(&sumout[dB.x * C + o], acc[4]);
        atomicAdd(&sumout[dB.y * C + o], acc[5]);
        atomicAdd(&sumout[dB.z * C + o], acc[6]);
        atomicAdd(&sumout[dB.w * C + o], acc[7]);
    }
}

// CBT: out[i,j] = sum_k |h[i,k]-h[j,k]|. 256-thread blocks, 64x64 tiles.
__global__ __launch_bounds__(256) void cbt_kernel(const float* __restrict__ h,
                                                  float* __restrict__ out) {
    __shared__ float hj_s[64][33];
    __shared__ float hi_s[64 * 32];
    const int lane = threadIdx.x & 63;
    const int w = threadIdx.x >> 6;
    const int j0 = blockIdx.x * 64;
    const int i0 = blockIdx.y * 64;
    for (int t = threadIdx.x; t < 64 * 32; t += 256) {
        hj_s[t >> 5][t & 31] = h[j0 * 32 + t];
        hi_s[t] = h[i0 * 32 + t];
    }
    __syncthreads();
    float hj[32];
#pragma unroll
    for (int k = 0; k < 32; k++) hj[k] = hj_s[lane][k];
    const int j = j0 + lane;
#pragma unroll 4
    for (int ii = w * 16; ii < w * 16 + 16; ii++) {
        float acc = 0.0f;
#pragma unroll
        for (int k = 0; k < 32; k++) {
            acc += fabsf(hi_s[ii * 32 + k] - hj[k]);
        }
        out[(size_t)(i0 + ii) * N_NODES + j] = acc;
    }
}

extern "C" void kernel_launch(void* const* d_in, const int* in_sizes, int n_in,
                              void* d_out, int out_size, void* d_ws, size_t ws_size,
                              hipStream_t stream) {
    const float* x         = (const float*)d_in[0];
    const float* edge_attr = (const float*)d_in[1];
    const int*   edge_idx  = (const int*)d_in[2];
    const float* W1 = (const float*)d_in[3];
    const float* b1 = (const float*)d_in[4];
    const float* root1 = (const float*)d_in[5];
    const float* bias1 = (const float*)d_in[6];
    const float* W2 = (const float*)d_in[7];
    const float* b2 = (const float*)d_in[8];
    const float* root2 = (const float*)d_in[9];
    const float* bias2 = (const float*)d_in[10];
    const float* W3 = (const float*)d_in[11];
    const float* b3 = (const float*)d_in[12];
    const float* root3 = (const float*)d_in[13];
    const float* bias3 = (const float*)d_in[14];

    const int* src = edge_idx;            // row 0
    const int* dst = edge_idx + N_EDGES;  // row 1

    float* ws   = (float*)d_ws;
    float* cnt  = ws;
    float* sum1 = ws + N_NODES;
    float* sum2 = sum1 + N_NODES * C;
    float* sum3 = sum2 + N_NODES * C;
    float* h1   = sum3 + N_NODES * C;
    float* h2   = h1 + N_NODES * C;
    float* h3   = h2 + N_NODES * C;

    // zero cnt + sum1..sum3 (contiguous, ~0.8 MB)
    hipMemsetAsync(d_ws, 0, (size_t)(N_NODES + 3 * N_NODES * C) * sizeof(float), stream);

    // Layer 1 (degree count fused)
    edge1_kernel<<<(N_EDGES * C) / 256, 256, 0, stream>>>(x, edge_attr, src, dst, W1, b1, sum1, cnt);
    node_kernel<1><<<(N_NODES * C) / 256, 256, 0, stream>>>(sum1, cnt, x, root1, bias1, h1);

    // Layer 2
    edge23_kernel<<<2048, 256, 0, stream>>>(h1, edge_attr, src, dst, W2, b2, sum2);
    node_kernel<C><<<(N_NODES * C) / 256, 256, 0, stream>>>(sum2, cnt, h1, root2, bias2, h2);

    // Layer 3
    edge23_kernel<<<2048, 256, 0, stream>>>(h2, edge_attr, src, dst, W3, b3, sum3);
    node_kernel<C><<<(N_NODES * C) / 256, 256, 0, stream>>>(sum3, cnt, h2, root3, bias3, h3);

    // CBT
    cbt_kernel<<<dim3(N_NODES / 64, N_NODES / 64), 256, 0, stream>>>(h3, (float*)d_out);
}

// Round 5
// 168.497 us; speedup vs baseline: 1.6034x; 1.0053x over previous
//
#include <hip/hip_runtime.h>

#define N_NODES 2048
#define N_EDGES 65536
#define NV 6
#define C 32

// ---------------------------------------------------------------------------
// ws layout (floats):
//   [0, N)            : cnt   (in-degree per node, fp32)   -- zeroed
//   [N, N+3*N*C)      : sum1, sum2, sum3 (scatter-add)     -- zeroed
//   [N+3NC, N+6NC)    : h1, h2, h3 (node features)         -- fully overwritten
// ---------------------------------------------------------------------------

// Layer 1 (in_c = 1), degree count fused (o==0 lane).
__global__ void edge1_kernel(const float* __restrict__ x,
                             const float* __restrict__ ea,
                             const int* __restrict__ src,
                             const int* __restrict__ dst,
                             const float* __restrict__ W1,
                             const float* __restrict__ b1,
                             float* __restrict__ sum1,
                             float* __restrict__ cnt) {
    int t = blockIdx.x * blockDim.x + threadIdx.x;
    int e = t >> 5, o = t & 31;
    if (e >= N_EDGES) return;
    const float* eap = ea + e * NV;
    float w = b1[o];
#pragma unroll
    for (int v = 0; v < NV; v++) w = fmaf(eap[v], W1[v * C + o], w);
    w = fmaxf(w, 0.0f);
    int d = dst[e];
    atomicAdd(&sum1[d * C + o], x[src[e]] * w);
    if (o == 0) atomicAdd(&cnt[d], 1.0f);
}

// Finalize a layer: h_out = relu(sum/max(cnt,1) + h_prev @ root + bias)
template <int IN_C>
__global__ void node_kernel(const float* __restrict__ sum,
                            const float* __restrict__ cnt,
                            const float* __restrict__ hprev,
                            const float* __restrict__ root,  // [IN_C, C]
                            const float* __restrict__ bias,  // [C]
                            float* __restrict__ hout) {
    int t = blockIdx.x * blockDim.x + threadIdx.x;  // N*C threads
    int n = t >> 5, o = t & 31;
    float inv = 1.0f / fmaxf(cnt[n], 1.0f);
    float acc = sum[t] * inv + bias[o];
#pragma unroll
    for (int i = 0; i < IN_C; i++) acc = fmaf(hprev[n * IN_C + i], root[i * C + o], acc);
    hout[t] = fmaxf(acc, 0.0f);
}

// Layers 2/3, W-IN-REGISTERS version.
// lane l: o = l&31, half = l>>5, i-slice [half*16, +16).
// Each lane permanently holds wreg[16][6] + breg[16] = exactly its j-loop
// footprint (112 VGPRs) -- W is never re-read after init. LDS is used only
// for the tiny per-wave h transpose (R4's proven conflict-free pattern:
// one contiguous 1KB b128 write, broadcast b128 reads).
// Grid 512 blocks = 2048 waves (full residency at 2 waves/SIMD);
// grid-stride: 4 eight-edge groups per wave, W init amortized.
__global__ __launch_bounds__(256) void edge23_kernel(
    const float* __restrict__ hprev,   // [N, 32]
    const float* __restrict__ ea,      // [E, 6]
    const int* __restrict__ src,
    const int* __restrict__ dst,
    const float* __restrict__ W,       // [NV, 1024]
    const float* __restrict__ b,       // [1024]
    float* __restrict__ sumout)        // [N, 32]
{
    __shared__ float hb[4][256];       // per-wave h staging (4 KB total)
    const int lane = threadIdx.x & 63;
    const int o = lane & 31;
    const int half = lane >> 5;
    const int i0 = half * 16;
    const int w = threadIdx.x >> 6;
    float* hbw = &hb[w][0];

    // W + bias resident in registers (coalesced init, L2-hot, once per wave)
    float wreg[16][6], breg[16];
#pragma unroll
    for (int j = 0; j < 16; j++) {
#pragma unroll
        for (int v = 0; v < 6; v++) wreg[j][v] = W[v * 1024 + (i0 + j) * C + o];
        breg[j] = b[(i0 + j) * C + o];
    }

    const int wid = (blockIdx.x * 256 + threadIdx.x) >> 6;  // 0..2047
    for (int g = wid; g < N_EDGES / 8; g += 2048) {
        const int e0 = g * 8;
        // stage h[src]: half 0 loads edges 0..3, half 1 loads edges 4..7,
        // then one fully contiguous 1KB wave write (conflict-free).
        const int4 sq = *(const int4*)&src[e0 + half * 4];
        float4 hq;
        hq.x = hprev[sq.x * C + o];
        hq.y = hprev[sq.y * C + o];
        hq.z = hprev[sq.z * C + o];
        hq.w = hprev[sq.w * C + o];
        *(float4*)&hbw[half * 128 + o * 4] = hq;

        float accs[8];
        const float4* eap4 = (const float4*)(ea + (size_t)e0 * NV);
#pragma unroll
        for (int sub = 0; sub < 2; sub++) {
            // 4 edges' attrs (24 floats)
            float eaf[24];
#pragma unroll
            for (int t = 0; t < 6; t++) *(float4*)&eaf[t * 4] = eap4[sub * 6 + t];
            float a0 = 0.0f, a1 = 0.0f, a2 = 0.0f, a3 = 0.0f;
#pragma unroll
            for (int j = 0; j < 16; j++) {
                const float4 hA = *(const float4*)&hbw[sub * 128 + (i0 + j) * 4];
                const float bb = breg[j];
                const float w0 = wreg[j][0], w1 = wreg[j][1], w2 = wreg[j][2];
                const float w3 = wreg[j][3], w4 = wreg[j][4], w5 = wreg[j][5];
                float t0 = bb, t1 = bb, t2 = bb, t3 = bb;
                t0 = fmaf(eaf[0],  w0, t0); t1 = fmaf(eaf[6],  w0, t1);
                t2 = fmaf(eaf[12], w0, t2); t3 = fmaf(eaf[18], w0, t3);
                t0 = fmaf(eaf[1],  w1, t0); t1 = fmaf(eaf[7],  w1, t1);
                t2 = fmaf(eaf[13], w1, t2); t3 = fmaf(eaf[19], w1, t3);
                t0 = fmaf(eaf[2],  w2, t0); t1 = fmaf(eaf[8],  w2, t1);
                t2 = fmaf(eaf[14], w2, t2); t3 = fmaf(eaf[20], w2, t3);
                t0 = fmaf(eaf[3],  w3, t0); t1 = fmaf(eaf[9],  w3, t1);
                t2 = fmaf(eaf[15], w3, t2); t3 = fmaf(eaf[21], w3, t3);
                t0 = fmaf(eaf[4],  w4, t0); t1 = fmaf(eaf[10], w4, t1);
                t2 = fmaf(eaf[16], w4, t2); t3 = fmaf(eaf[22], w4, t3);
                t0 = fmaf(eaf[5],  w5, t0); t1 = fmaf(eaf[11], w5, t1);
                t2 = fmaf(eaf[17], w5, t2); t3 = fmaf(eaf[23], w5, t3);
                a0 = fmaf(hA.x, fmaxf(t0, 0.0f), a0);
                a1 = fmaf(hA.y, fmaxf(t1, 0.0f), a1);
                a2 = fmaf(hA.z, fmaxf(t2, 0.0f), a2);
                a3 = fmaf(hA.w, fmaxf(t3, 0.0f), a3);
            }
            accs[sub * 4 + 0] = a0; accs[sub * 4 + 1] = a1;
            accs[sub * 4 + 2] = a2; accs[sub * 4 + 3] = a3;
        }
#pragma unroll
        for (int k = 0; k < 8; k++) accs[k] += __shfl_down(accs[k], 32);

        const int4 dA = *(const int4*)&dst[e0];
        const int4 dB = *(const int4*)&dst[e0 + 4];
        if (lane < 32) {
            atomicAdd(&sumout[dA.x * C + o], accs[0]);
            atomicAdd(&sumout[dA.y * C + o], accs[1]);
            atomicAdd(&sumout[dA.z * C + o], accs[2]);
            atomicAdd(&sumout[dA.w * C + o], accs[3]);
            atomicAdd(&sumout[dB.x * C + o], accs[4]);
            atomicAdd(&sumout[dB.y * C + o], accs[5]);
            atomicAdd(&sumout[dB.z * C + o], accs[6]);
            atomicAdd(&sumout[dB.w * C + o], accs[7]);
        }
    }
}

// CBT: out[i,j] = sum_k |h[i,k]-h[j,k]|. 256-thread blocks, 64x64 tiles.
__global__ __launch_bounds__(256) void cbt_kernel(const float* __restrict__ h,
                                                  float* __restrict__ out) {
    __shared__ float hj_s[64][33];
    __shared__ float hi_s[64 * 32];
    const int lane = threadIdx.x & 63;
    const int w = threadIdx.x >> 6;
    const int j0 = blockIdx.x * 64;
    const int i0 = blockIdx.y * 64;
    for (int t = threadIdx.x; t < 64 * 32; t += 256) {
        hj_s[t >> 5][t & 31] = h[j0 * 32 + t];
        hi_s[t] = h[i0 * 32 + t];
    }
    __syncthreads();
    float hj[32];
#pragma unroll
    for (int k = 0; k < 32; k++) hj[k] = hj_s[lane][k];
    const int j = j0 + lane;
#pragma unroll 4
    for (int ii = w * 16; ii < w * 16 + 16; ii++) {
        float acc = 0.0f;
#pragma unroll
        for (int k = 0; k < 32; k++) {
            acc += fabsf(hi_s[ii * 32 + k] - hj[k]);
        }
        out[(size_t)(i0 + ii) * N_NODES + j] = acc;
    }
}

extern "C" void kernel_launch(void* const* d_in, const int* in_sizes, int n_in,
                              void* d_out, int out_size, void* d_ws, size_t ws_size,
                              hipStream_t stream) {
    const float* x         = (const float*)d_in[0];
    const float* edge_attr = (const float*)d_in[1];
    const int*   edge_idx  = (const int*)d_in[2];
    const float* W1 = (const float*)d_in[3];
    const float* b1 = (const float*)d_in[4];
    const float* root1 = (const float*)d_in[5];
    const float* bias1 = (const float*)d_in[6];
    const float* W2 = (const float*)d_in[7];
    const float* b2 = (const float*)d_in[8];
    const float* root2 = (const float*)d_in[9];
    const float* bias2 = (const float*)d_in[10];
    const float* W3 = (const float*)d_in[11];
    const float* b3 = (const float*)d_in[12];
    const float* root3 = (const float*)d_in[13];
    const float* bias3 = (const float*)d_in[14];

    const int* src = edge_idx;            // row 0
    const int* dst = edge_idx + N_EDGES;  // row 1

    float* ws   = (float*)d_ws;
    float* cnt  = ws;
    float* sum1 = ws + N_NODES;
    float* sum2 = sum1 + N_NODES * C;
    float* sum3 = sum2 + N_NODES * C;
    float* h1   = sum3 + N_NODES * C;
    float* h2   = h1 + N_NODES * C;
    float* h3   = h2 + N_NODES * C;

    // zero cnt + sum1..sum3 (contiguous, ~0.8 MB)
    hipMemsetAsync(d_ws, 0, (size_t)(N_NODES + 3 * N_NODES * C) * sizeof(float), stream);

    // Layer 1 (degree count fused)
    edge1_kernel<<<(N_EDGES * C) / 256, 256, 0, stream>>>(x, edge_attr, src, dst, W1, b1, sum1, cnt);
    node_kernel<1><<<(N_NODES * C) / 256, 256, 0, stream>>>(sum1, cnt, x, root1, bias1, h1);

    // Layer 2
    edge23_kernel<<<512, 256, 0, stream>>>(h1, edge_attr, src, dst, W2, b2, sum2);
    node_kernel<C><<<(N_NODES * C) / 256, 256, 0, stream>>>(sum2, cnt, h1, root2, bias2, h2);

    // Layer 3
    edge23_kernel<<<512, 256, 0, stream>>>(h2, edge_attr, src, dst, W3, b3, sum3);
    node_kernel<C><<<(N_NODES * C) / 256, 256, 0, stream>>>(sum3, cnt, h2, root3, bias3, h3);

    // CBT
    cbt_kernel<<<dim3(N_NODES / 64, N_NODES / 64), 256, 0, stream>>>(h3, (float*)d_out);
}